// Round 1
// baseline (500.347 us; speedup 1.0000x reference)
//
#include <hip/hip_runtime.h>
#include <stdint.h>

typedef unsigned int uint;
typedef unsigned short ushort;
typedef unsigned char uchar;
typedef __attribute__((ext_vector_type(8))) short bf16x8;
typedef __attribute__((ext_vector_type(4))) float f32x4;

__device__ __forceinline__ ushort f2bf(float f) {
  uint u = __builtin_bit_cast(uint, f);
  return (ushort)((u + 0x7FFFu + ((u >> 16) & 1u)) >> 16);
}

// 8 mask bytes (any nonzero == true) -> bf16x8 of 1.0/0.0, plus packed u16
// count accumulator (lo/hi lanes each hold partial popcounts, <= 256 total).
__device__ __forceinline__ bf16x8 cvt8(uint lo, uint hi, uint& cacc) {
  // spread bytes into u16 lanes: x = b_even | b_odd<<16 (src0==0 supplies zeros)
  uint x0 = __builtin_amdgcn_perm(0u, lo, 0x04010400u);  // b0 | b1<<16
  uint x1 = __builtin_amdgcn_perm(0u, lo, 0x04030402u);  // b2 | b3<<16
  uint x2 = __builtin_amdgcn_perm(0u, hi, 0x04010400u);
  uint x3 = __builtin_amdgcn_perm(0u, hi, 0x04030402u);
  // nonzero-detect per u16 lane: (v+255)>>8 gives 1 iff v>=1 (v<=255)
  uint n0 = ((x0 + 0x00FF00FFu) >> 8) & 0x00010001u;
  uint n1 = ((x1 + 0x00FF00FFu) >> 8) & 0x00010001u;
  uint n2 = ((x2 + 0x00FF00FFu) >> 8) & 0x00010001u;
  uint n3 = ((x3 + 0x00FF00FFu) >> 8) & 0x00010001u;
  cacc += n0 + n1 + n2 + n3;
  uint4 o;
  o.x = n0 * 0x3F80u; o.y = n1 * 0x3F80u;  // 0x3F80 = bf16(1.0)
  o.z = n2 * 0x3F80u; o.w = n3 * 0x3F80u;
  return __builtin_bit_cast(bf16x8, o);
}

// 8 mask dwords (int/float bool) -> bf16x8 + count
__device__ __forceinline__ bf16x8 cvt8w(uint4 a, uint4 b, uint& cnt) {
  bf16x8 r;
  r[0] = a.x ? (short)0x3F80 : (short)0; cnt += (a.x != 0u);
  r[1] = a.y ? (short)0x3F80 : (short)0; cnt += (a.y != 0u);
  r[2] = a.z ? (short)0x3F80 : (short)0; cnt += (a.z != 0u);
  r[3] = a.w ? (short)0x3F80 : (short)0; cnt += (a.w != 0u);
  r[4] = b.x ? (short)0x3F80 : (short)0; cnt += (b.x != 0u);
  r[5] = b.y ? (short)0x3F80 : (short)0; cnt += (b.y != 0u);
  r[6] = b.z ? (short)0x3F80 : (short)0; cnt += (b.z != 0u);
  r[7] = b.w ? (short)0x3F80 : (short)0; cnt += (b.w != 0u);
  return r;
}

// ---------------------------------------------------------------------------
// Mask element width detection (4-byte int/float vs 1-byte bool). Coalesced.
__global__ __launch_bounds__(256) void k_detect(
    const uint4* __restrict__ m, int* __restrict__ esz_out) {
  __shared__ int s_ok;
  if (threadIdx.x == 0) s_ok = 1;
  __syncthreads();
  int ok = 1;
#pragma unroll
  for (int i = 0; i < 16; ++i) {
    uint4 v = m[i * 256 + threadIdx.x];
    if (!(v.x <= 1u || v.x == 0x3F800000u)) ok = 0;
    if (!(v.y <= 1u || v.y == 0x3F800000u)) ok = 0;
    if (!(v.z <= 1u || v.z == 0x3F800000u)) ok = 0;
    if (!(v.w <= 1u || v.w == 0x3F800000u)) ok = 0;
  }
  if (!ok) atomicAnd(&s_ok, 0);
  __syncthreads();
  if (threadIdx.x == 0) *esz_out = s_ok ? 4 : 1;
}

// ---------------------------------------------------------------------------
// Fused prep: features f32->bf16 + transpose all weights to bf16 [n][k].
__global__ __launch_bounds__(256) void k_prep(
    const float4* __restrict__ fin, ushort* __restrict__ fout,
    const float* __restrict__ We, const float* __restrict__ Ws,
    const float* __restrict__ Wm, const float* __restrict__ Wx,
    ushort* __restrict__ Te, ushort* __restrict__ Ts,
    ushort* __restrict__ Tm, ushort* __restrict__ Tx) {
  const int tid = blockIdx.x * 256 + threadIdx.x;  // grid 704*256 = 180224
  for (int i = tid; i < 524288; i += 180224) {
    float4 v = fin[i];
    ushort4 o;
    o.x = f2bf(v.x); o.y = f2bf(v.y); o.z = f2bf(v.z); o.w = f2bf(v.w);
    *(ushort4*)&fout[(size_t)i * 4] = o;
  }
  int i = tid;
  if (i < 65536) { int n = i >> 7, k = i & 127; Te[i] = f2bf(We[k * 512 + n]); return; }
  i -= 65536;
  if (i < 49152) { int n = i / 384, k = i - n * 384; Ts[i] = f2bf(Ws[k * 128 + n]); return; }
  i -= 49152;
  if (i < 32768) { int n = i >> 8, k = i & 255; Tm[i] = f2bf(Wm[k * 128 + n]); return; }
  i -= 32768;
  if (i < 32768) { int n = i >> 8, k = i & 255; Tx[i] = f2bf(Wx[k * 128 + n]); return; }
}

// ---------------------------------------------------------------------------
// Encoder GEMM, LDS-free: fragments loaded directly from global in MFMA
// layout. K=128 fully unrolled, zero barriers. Tile 64x128, grid(256, 4).
__global__ __launch_bounds__(256) void k_enc(
    const ushort* __restrict__ featbf, const ushort* __restrict__ WTe,
    const float* __restrict__ bias, ushort* __restrict__ origin,
    ushort* __restrict__ eT0, ushort* __restrict__ eT1, ushort* __restrict__ eT2) {
  const int t = threadIdx.x;
  const int gm0 = blockIdx.x * 64;
  const int y = blockIdx.y;
  const int lane = t & 63, wave = t >> 6;
  const int m0w = (wave >> 1) * 32, n0w = (wave & 1) * 64;
  const int quad = lane >> 4, lr = lane & 15;
  const ushort* a0p = featbf + (size_t)(gm0 + m0w + lr) * 128 + quad * 8;
  const ushort* a1p = a0p + 16 * 128;
  bf16x8 af0[4], af1[4];
#pragma unroll
  for (int kc = 0; kc < 4; ++kc) {
    af0[kc] = *(const bf16x8*)(a0p + kc * 32);
    af1[kc] = *(const bf16x8*)(a1p + kc * 32);
  }
  f32x4 acc[2][4] = {};
#pragma unroll
  for (int j = 0; j < 4; ++j) {
    const ushort* bp = WTe + (size_t)(y * 128 + n0w + j * 16 + lr) * 128 + quad * 8;
#pragma unroll
    for (int kc = 0; kc < 4; ++kc) {
      bf16x8 bv = *(const bf16x8*)(bp + kc * 32);
      acc[0][j] = __builtin_amdgcn_mfma_f32_16x16x32_bf16(af0[kc], bv, acc[0][j], 0, 0, 0);
      acc[1][j] = __builtin_amdgcn_mfma_f32_16x16x32_bf16(af1[kc], bv, acc[1][j], 0, 0, 0);
    }
  }
  if (y == 0) {
#pragma unroll
    for (int i = 0; i < 2; ++i)
#pragma unroll
      for (int j = 0; j < 4; ++j) {
        int n = n0w + j * 16 + lr;
        float bb = bias[n];
        int mb = gm0 + m0w + i * 16 + quad * 4;
#pragma unroll
        for (int r = 0; r < 4; ++r)
          origin[(size_t)(mb + r) * 128 + n] = f2bf(acc[i][j][r] + bb);
      }
  } else {
    ushort* eT = (y == 1) ? eT0 : (y == 2) ? eT1 : eT2;
#pragma unroll
    for (int i = 0; i < 2; ++i)
#pragma unroll
      for (int j = 0; j < 4; ++j) {
        int n = n0w + j * 16 + lr;
        float bb = bias[y * 128 + n];
        int mb = gm0 + m0w + i * 16 + quad * 4;
        ushort4 o;
        o.x = f2bf(acc[i][j][0] + bb);
        o.y = f2bf(acc[i][j][1] + bb);
        o.z = f2bf(acc[i][j][2] + bb);
        o.w = f2bf(acc[i][j][3] + bb);
        *(ushort4*)&eT[(size_t)n * 16384 + mb] = o;  // vectorized transposed store
      }
  }
}

// ---------------------------------------------------------------------------
// Masked mean, LDS-free: mask and eT fragments loaded directly from global in
// MFMA fragment layout (32B-contiguous per quad-group). ZERO barriers in the
// main loop; 1-deep register prefetch of the HBM-sourced mask bytes. Degree
// via packed-u16 popcount + shfl_xor reduce. Grid (32, 8, 3).
__global__ __launch_bounds__(256, 3) void k_mm(
    const void* __restrict__ mp, const void* __restrict__ ms,
    const void* __restrict__ mt,
    const ushort* __restrict__ eT0, const ushort* __restrict__ eT1,
    const ushort* __restrict__ eT2,
    ushort* __restrict__ P, ushort* __restrict__ S, ushort* __restrict__ T,
    const int* __restrict__ esz_p) {
  __shared__ uint degs[64];
  const int t = threadIdx.x;
  const int mtile = blockIdx.x, b = blockIdx.y, mid = blockIdx.z;
  const void* mask = (mid == 0) ? mp : (mid == 1) ? ms : mt;
  const ushort* eT = (mid == 0) ? eT0 : (mid == 1) ? eT1 : eT2;
  ushort* outp = (mid == 0) ? P : (mid == 1) ? S : T;
  const int esz = *esz_p;
  const size_t rowbase = (size_t)b * 2048 + mtile * 64;
  const int lane = t & 63, wave = t >> 6;
  const int m0w = (wave >> 1) * 32, n0w = (wave & 1) * 64;
  const int quad = lane >> 4, lr = lane & 15;
  const int r0 = m0w + lr, r1 = m0w + 16 + lr;
  const ushort* bp0 = eT + (size_t)(n0w + lr) * 16384 + (size_t)b * 2048 + quad * 8;
  const ushort* bp1 = bp0 + 16 * 16384;
  const ushort* bp2 = bp0 + 32 * 16384;
  const ushort* bp3 = bp0 + 48 * 16384;
  f32x4 acc[2][4] = {};
  uint cacc0 = 0, cacc1 = 0;

  if (esz == 1) {
    const uchar* ma = (const uchar*)mask + (rowbase + r0) * 2048 + quad * 8;
    const uchar* mb = (const uchar*)mask + (rowbase + r1) * 2048 + quad * 8;
    uint2 ra0 = *(const uint2*)(ma);
    uint2 ra1 = *(const uint2*)(ma + 32);
    uint2 rb0 = *(const uint2*)(mb);
    uint2 rb1 = *(const uint2*)(mb + 32);
#pragma unroll 2
    for (int k0 = 0; k0 < 2048; k0 += 64) {
      uint2 na0 = {}, na1 = {}, nb0 = {}, nb1 = {};
      if (k0 + 64 < 2048) {  // prefetch next step's mask bytes (HBM latency)
        na0 = *(const uint2*)(ma + k0 + 64);
        na1 = *(const uint2*)(ma + k0 + 96);
        nb0 = *(const uint2*)(mb + k0 + 64);
        nb1 = *(const uint2*)(mb + k0 + 96);
      }
#pragma unroll
      for (int kc = 0; kc < 2; ++kc) {
        bf16x8 bv0 = *(const bf16x8*)(bp0 + k0 + kc * 32);
        bf16x8 bv1 = *(const bf16x8*)(bp1 + k0 + kc * 32);
        bf16x8 bv2 = *(const bf16x8*)(bp2 + k0 + kc * 32);
        bf16x8 bv3 = *(const bf16x8*)(bp3 + k0 + kc * 32);
        uint2 wa = kc ? ra1 : ra0;
        uint2 wb = kc ? rb1 : rb0;
        bf16x8 a0 = cvt8(wa.x, wa.y, cacc0);
        bf16x8 a1 = cvt8(wb.x, wb.y, cacc1);
        acc[0][0] = __builtin_amdgcn_mfma_f32_16x16x32_bf16(a0, bv0, acc[0][0], 0, 0, 0);
        acc[1][0] = __builtin_amdgcn_mfma_f32_16x16x32_bf16(a1, bv0, acc[1][0], 0, 0, 0);
        acc[0][1] = __builtin_amdgcn_mfma_f32_16x16x32_bf16(a0, bv1, acc[0][1], 0, 0, 0);
        acc[1][1] = __builtin_amdgcn_mfma_f32_16x16x32_bf16(a1, bv1, acc[1][1], 0, 0, 0);
        acc[0][2] = __builtin_amdgcn_mfma_f32_16x16x32_bf16(a0, bv2, acc[0][2], 0, 0, 0);
        acc[1][2] = __builtin_amdgcn_mfma_f32_16x16x32_bf16(a1, bv2, acc[1][2], 0, 0, 0);
        acc[0][3] = __builtin_amdgcn_mfma_f32_16x16x32_bf16(a0, bv3, acc[0][3], 0, 0, 0);
        acc[1][3] = __builtin_amdgcn_mfma_f32_16x16x32_bf16(a1, bv3, acc[1][3], 0, 0, 0);
      }
      ra0 = na0; ra1 = na1; rb0 = nb0; rb1 = nb1;
    }
  } else {
    const uint* ma = (const uint*)mask + (rowbase + r0) * 2048 + quad * 8;
    const uint* mb = (const uint*)mask + (rowbase + r1) * 2048 + quad * 8;
    for (int k0 = 0; k0 < 2048; k0 += 64) {
#pragma unroll
      for (int kc = 0; kc < 2; ++kc) {
        uint4 wa0 = *(const uint4*)(ma + k0 + kc * 32);
        uint4 wa1 = *(const uint4*)(ma + k0 + kc * 32 + 4);
        uint4 wb0 = *(const uint4*)(mb + k0 + kc * 32);
        uint4 wb1 = *(const uint4*)(mb + k0 + kc * 32 + 4);
        bf16x8 bv0 = *(const bf16x8*)(bp0 + k0 + kc * 32);
        bf16x8 bv1 = *(const bf16x8*)(bp1 + k0 + kc * 32);
        bf16x8 bv2 = *(const bf16x8*)(bp2 + k0 + kc * 32);
        bf16x8 bv3 = *(const bf16x8*)(bp3 + k0 + kc * 32);
        bf16x8 a0 = cvt8w(wa0, wa1, cacc0);
        bf16x8 a1 = cvt8w(wb0, wb1, cacc1);
        acc[0][0] = __builtin_amdgcn_mfma_f32_16x16x32_bf16(a0, bv0, acc[0][0], 0, 0, 0);
        acc[1][0] = __builtin_amdgcn_mfma_f32_16x16x32_bf16(a1, bv0, acc[1][0], 0, 0, 0);
        acc[0][1] = __builtin_amdgcn_mfma_f32_16x16x32_bf16(a0, bv1, acc[0][1], 0, 0, 0);
        acc[1][1] = __builtin_amdgcn_mfma_f32_16x16x32_bf16(a1, bv1, acc[1][1], 0, 0, 0);
        acc[0][2] = __builtin_amdgcn_mfma_f32_16x16x32_bf16(a0, bv2, acc[0][2], 0, 0, 0);
        acc[1][2] = __builtin_amdgcn_mfma_f32_16x16x32_bf16(a1, bv2, acc[1][2], 0, 0, 0);
        acc[0][3] = __builtin_amdgcn_mfma_f32_16x16x32_bf16(a0, bv3, acc[0][3], 0, 0, 0);
        acc[1][3] = __builtin_amdgcn_mfma_f32_16x16x32_bf16(a1, bv3, acc[1][3], 0, 0, 0);
      }
    }
  }

  // Degree: per-thread partial (rows r0, r1) -> sum over the 4 quad lanes.
  int c0, c1;
  if (esz == 1) {
    c0 = (int)((cacc0 & 0xFFFFu) + (cacc0 >> 16));
    c1 = (int)((cacc1 & 0xFFFFu) + (cacc1 >> 16));
  } else {
    c0 = (int)cacc0;
    c1 = (int)cacc1;
  }
  c0 += __shfl_xor(c0, 16); c0 += __shfl_xor(c0, 32);
  c1 += __shfl_xor(c1, 16); c1 += __shfl_xor(c1, 32);
  if ((wave & 1) == 0 && quad == 0) { degs[r0] = (uint)c0; degs[r1] = (uint)c1; }
  __syncthreads();

#pragma unroll
  for (int i = 0; i < 2; ++i)
#pragma unroll
    for (int r = 0; r < 4; ++r) {
      int ml = m0w + i * 16 + quad * 4 + r;
      uint d = degs[ml];
      float inv = 1.0f / (float)(d > 0u ? d : 1u);
#pragma unroll
      for (int j = 0; j < 4; ++j) {
        int n = n0w + j * 16 + lr;
        outp[(rowbase + ml) * 128 + n] = f2bf(acc[i][j][r] * inv);
      }
    }
}

// ---------------------------------------------------------------------------
// Generic LDS-free GEMM body: A = virtual concat of up to 3 bf16 [M,128]
// sources along K, B = WT bf16 [128][K] (+bias). No barriers.
__device__ __forceinline__ void gemm_body(
    const ushort* __restrict__ A0, const ushort* __restrict__ A1,
    const ushort* __restrict__ A2, const ushort* __restrict__ Bsrc,
    int bstride, int K, const float* __restrict__ bias,
    void* __restrict__ out, int out_f32, int gm0, int t) {
  const int lane = t & 63, wave = t >> 6;
  const int m0w = (wave >> 1) * 32, n0w = (wave & 1) * 64;
  const int quad = lane >> 4, lr = lane & 15;
  const ushort* bbase = Bsrc + (size_t)(n0w + lr) * bstride + quad * 8;
  f32x4 acc[2][4] = {};
  for (int k0 = 0; k0 < K; k0 += 64) {
    const int seg = k0 >> 7;
    const ushort* Ap = (seg == 0) ? A0 : (seg == 1) ? A1 : A2;
    const int ko = k0 & 127;
    const ushort* a0p = Ap + (size_t)(gm0 + m0w + lr) * 128 + ko + quad * 8;
    const ushort* a1p = a0p + 16 * 128;
#pragma unroll
    for (int kc = 0; kc < 2; ++kc) {
      bf16x8 av0 = *(const bf16x8*)(a0p + kc * 32);
      bf16x8 av1 = *(const bf16x8*)(a1p + kc * 32);
      bf16x8 b0 = *(const bf16x8*)(bbase + k0 + kc * 32);
      bf16x8 b1 = *(const bf16x8*)(bbase + (size_t)16 * bstride + k0 + kc * 32);
      bf16x8 b2 = *(const bf16x8*)(bbase + (size_t)32 * bstride + k0 + kc * 32);
      bf16x8 b3 = *(const bf16x8*)(bbase + (size_t)48 * bstride + k0 + kc * 32);
      acc[0][0] = __builtin_amdgcn_mfma_f32_16x16x32_bf16(av0, b0, acc[0][0], 0, 0, 0);
      acc[1][0] = __builtin_amdgcn_mfma_f32_16x16x32_bf16(av1, b0, acc[1][0], 0, 0, 0);
      acc[0][1] = __builtin_amdgcn_mfma_f32_16x16x32_bf16(av0, b1, acc[0][1], 0, 0, 0);
      acc[1][1] = __builtin_amdgcn_mfma_f32_16x16x32_bf16(av1, b1, acc[1][1], 0, 0, 0);
      acc[0][2] = __builtin_amdgcn_mfma_f32_16x16x32_bf16(av0, b2, acc[0][2], 0, 0, 0);
      acc[1][2] = __builtin_amdgcn_mfma_f32_16x16x32_bf16(av1, b2, acc[1][2], 0, 0, 0);
      acc[0][3] = __builtin_amdgcn_mfma_f32_16x16x32_bf16(av0, b3, acc[0][3], 0, 0, 0);
      acc[1][3] = __builtin_amdgcn_mfma_f32_16x16x32_bf16(av1, b3, acc[1][3], 0, 0, 0);
    }
  }
#pragma unroll
  for (int i = 0; i < 2; ++i)
#pragma unroll
    for (int j = 0; j < 4; ++j) {
      const int n = n0w + j * 16 + lr;
      const float bb = bias[n];
      const int mb = gm0 + m0w + i * 16 + quad * 4;
      if (out_f32) {
#pragma unroll
        for (int r = 0; r < 4; ++r)
          ((float*)out)[(size_t)(mb + r) * 128 + n] = acc[i][j][r] + bb;
      } else {
#pragma unroll
        for (int r = 0; r < 4; ++r)
          ((ushort*)out)[(size_t)(mb + r) * 128 + n] = f2bf(acc[i][j][r] + bb);
      }
    }
}

// X and Y GEMMs fused into one launch (independent): grid (256, 2).
__global__ __launch_bounds__(256) void k_xy(
    const ushort* __restrict__ P, const ushort* __restrict__ origin,
    const ushort* __restrict__ S, const ushort* __restrict__ T,
    const ushort* __restrict__ WTs, const ushort* __restrict__ WTm,
    const float* __restrict__ bs, const float* __restrict__ bm,
    ushort* __restrict__ X, ushort* __restrict__ Y) {
  const int gm0 = blockIdx.x * 64;
  if (blockIdx.y == 0)
    gemm_body(P, origin, S, WTs, 384, 384, bs, X, 0, gm0, threadIdx.x);
  else
    gemm_body(origin, T, nullptr, WTm, 256, 256, bm, Y, 0, gm0, threadIdx.x);
}

__global__ __launch_bounds__(256) void k_mix(
    const ushort* __restrict__ X, const ushort* __restrict__ Y,
    const ushort* __restrict__ WTx, const float* __restrict__ bx,
    float* __restrict__ out) {
  gemm_body(X, Y, nullptr, WTx, 256, 256, bx, out, 1, blockIdx.x * 64, threadIdx.x);
}

// ---------------------------------------------------------------------------
extern "C" void kernel_launch(void* const* d_in, const int* in_sizes, int n_in,
                              void* d_out, int out_size, void* d_ws,
                              size_t ws_size, hipStream_t stream) {
  const float* features = (const float*)d_in[0];
  const void* pred = d_in[1];
  const void* succ = d_in[2];
  const void* same = d_in[3];
  const float* W_enc = (const float*)d_in[4];
  const float* b_enc = (const float*)d_in[5];
  const float* W_space = (const float*)d_in[6];
  const float* b_space = (const float*)d_in[7];
  const float* W_same = (const float*)d_in[8];
  const float* b_same = (const float*)d_in[9];
  const float* W_mix = (const float*)d_in[10];
  const float* b_mix = (const float*)d_in[11];

  const size_t M = 16384;
  ushort* w = (ushort*)d_ws;
  ushort* feat_bf = w;  w += M * 128;
  ushort* WT_enc = w;   w += 512 * 128;
  ushort* WT_space = w; w += 128 * 384;
  ushort* WT_same = w;  w += 128 * 256;
  ushort* WT_mix = w;   w += 128 * 256;
  ushort* origin = w;   w += M * 128;
  ushort* eT0 = w;      w += M * 128;
  ushort* eT1 = w;      w += M * 128;
  ushort* eT2 = w;      w += M * 128;
  ushort* P = w;        w += M * 128;
  ushort* S = w;        w += M * 128;
  ushort* T = w;        w += M * 128;
  ushort* X = w;        w += M * 128;
  ushort* Y = w;        w += M * 128;
  int* esz = (int*)w;

  k_detect<<<1, 256, 0, stream>>>((const uint4*)pred, esz);
  k_prep<<<704, 256, 0, stream>>>((const float4*)features, feat_bf,
                                  W_enc, W_space, W_same, W_mix,
                                  WT_enc, WT_space, WT_same, WT_mix);
  k_enc<<<dim3(256, 4), 256, 0, stream>>>(feat_bf, WT_enc, b_enc,
                                          origin, eT0, eT1, eT2);
  k_mm<<<dim3(32, 8, 3), 256, 0, stream>>>(pred, succ, same, eT0, eT1, eT2,
                                           P, S, T, esz);
  k_xy<<<dim3(256, 2), 256, 0, stream>>>(P, origin, S, T, WT_space, WT_same,
                                         b_space, b_same, X, Y);
  k_mix<<<256, 256, 0, stream>>>(X, Y, WT_mix, b_mix, (float*)d_out);
}

// Round 2
// 493.880 us; speedup vs baseline: 1.0131x; 1.0131x over previous
//
#include <hip/hip_runtime.h>
#include <stdint.h>

typedef unsigned int uint;
typedef unsigned short ushort;
typedef unsigned char uchar;
typedef __attribute__((ext_vector_type(8))) short bf16x8;
typedef __attribute__((ext_vector_type(4))) float f32x4;

__device__ __forceinline__ ushort f2bf(float f) {
  uint u = __builtin_bit_cast(uint, f);
  return (ushort)((u + 0x7FFFu + ((u >> 16) & 1u)) >> 16);
}

// 8 mask bytes (any nonzero == true) -> bf16x8 of 1.0/0.0, plus packed u16
// count accumulator (lo/hi u16 halves hold partial popcounts).
__device__ __forceinline__ bf16x8 cvt8(uint lo, uint hi, uint& cacc) {
  uint x0 = __builtin_amdgcn_perm(0u, lo, 0x04010400u);  // b0 | b1<<16
  uint x1 = __builtin_amdgcn_perm(0u, lo, 0x04030402u);  // b2 | b3<<16
  uint x2 = __builtin_amdgcn_perm(0u, hi, 0x04010400u);
  uint x3 = __builtin_amdgcn_perm(0u, hi, 0x04030402u);
  uint n0 = ((x0 + 0x00FF00FFu) >> 8) & 0x00010001u;
  uint n1 = ((x1 + 0x00FF00FFu) >> 8) & 0x00010001u;
  uint n2 = ((x2 + 0x00FF00FFu) >> 8) & 0x00010001u;
  uint n3 = ((x3 + 0x00FF00FFu) >> 8) & 0x00010001u;
  cacc += n0 + n1 + n2 + n3;
  uint4 o;
  o.x = n0 * 0x3F80u; o.y = n1 * 0x3F80u;  // 0x3F80 = bf16(1.0)
  o.z = n2 * 0x3F80u; o.w = n3 * 0x3F80u;
  return __builtin_bit_cast(bf16x8, o);
}

// 8 mask dwords (int/float bool) -> bf16x8 + count
__device__ __forceinline__ bf16x8 cvt8w(uint4 a, uint4 b, uint& cnt) {
  bf16x8 r;
  r[0] = a.x ? (short)0x3F80 : (short)0; cnt += (a.x != 0u);
  r[1] = a.y ? (short)0x3F80 : (short)0; cnt += (a.y != 0u);
  r[2] = a.z ? (short)0x3F80 : (short)0; cnt += (a.z != 0u);
  r[3] = a.w ? (short)0x3F80 : (short)0; cnt += (a.w != 0u);
  r[4] = b.x ? (short)0x3F80 : (short)0; cnt += (b.x != 0u);
  r[5] = b.y ? (short)0x3F80 : (short)0; cnt += (b.y != 0u);
  r[6] = b.z ? (short)0x3F80 : (short)0; cnt += (b.z != 0u);
  r[7] = b.w ? (short)0x3F80 : (short)0; cnt += (b.w != 0u);
  return r;
}

// ---------------------------------------------------------------------------
__global__ __launch_bounds__(256) void k_detect(
    const uint4* __restrict__ m, int* __restrict__ esz_out) {
  __shared__ int s_ok;
  if (threadIdx.x == 0) s_ok = 1;
  __syncthreads();
  int ok = 1;
#pragma unroll
  for (int i = 0; i < 16; ++i) {
    uint4 v = m[i * 256 + threadIdx.x];
    if (!(v.x <= 1u || v.x == 0x3F800000u)) ok = 0;
    if (!(v.y <= 1u || v.y == 0x3F800000u)) ok = 0;
    if (!(v.z <= 1u || v.z == 0x3F800000u)) ok = 0;
    if (!(v.w <= 1u || v.w == 0x3F800000u)) ok = 0;
  }
  if (!ok) atomicAnd(&s_ok, 0);
  __syncthreads();
  if (threadIdx.x == 0) *esz_out = s_ok ? 4 : 1;
}

// ---------------------------------------------------------------------------
__global__ __launch_bounds__(256) void k_prep(
    const float4* __restrict__ fin, ushort* __restrict__ fout,
    const float* __restrict__ We, const float* __restrict__ Ws,
    const float* __restrict__ Wm, const float* __restrict__ Wx,
    ushort* __restrict__ Te, ushort* __restrict__ Ts,
    ushort* __restrict__ Tm, ushort* __restrict__ Tx) {
  const int tid = blockIdx.x * 256 + threadIdx.x;  // grid 704*256 = 180224
  for (int i = tid; i < 524288; i += 180224) {
    float4 v = fin[i];
    ushort4 o;
    o.x = f2bf(v.x); o.y = f2bf(v.y); o.z = f2bf(v.z); o.w = f2bf(v.w);
    *(ushort4*)&fout[(size_t)i * 4] = o;
  }
  int i = tid;
  if (i < 65536) { int n = i >> 7, k = i & 127; Te[i] = f2bf(We[k * 512 + n]); return; }
  i -= 65536;
  if (i < 49152) { int n = i / 384, k = i - n * 384; Ts[i] = f2bf(Ws[k * 128 + n]); return; }
  i -= 49152;
  if (i < 32768) { int n = i >> 8, k = i & 255; Tm[i] = f2bf(Wm[k * 128 + n]); return; }
  i -= 32768;
  if (i < 32768) { int n = i >> 8, k = i & 255; Tx[i] = f2bf(Wx[k * 128 + n]); return; }
}

// ---------------------------------------------------------------------------
// Encoder GEMM, LDS-free loads (all operands L2-resident); eT outputs go
// through a swizzled LDS transpose so global stores are 16B-contiguous.
__global__ __launch_bounds__(256) void k_enc(
    const ushort* __restrict__ featbf, const ushort* __restrict__ WTe,
    const float* __restrict__ bias, ushort* __restrict__ origin,
    ushort* __restrict__ eT0, ushort* __restrict__ eT1, ushort* __restrict__ eT2) {
  __shared__ ushort tr[128 * 64];  // [n][m] with 16B-chunk XOR swizzle
  const int t = threadIdx.x;
  const int gm0 = blockIdx.x * 64;
  const int y = blockIdx.y;
  const int lane = t & 63, wave = t >> 6;
  const int m0w = (wave >> 1) * 32, n0w = (wave & 1) * 64;
  const int quad = lane >> 4, lr = lane & 15;
  const ushort* a0p = featbf + (size_t)(gm0 + m0w + lr) * 128 + quad * 8;
  const ushort* a1p = a0p + 16 * 128;
  bf16x8 af0[4], af1[4];
#pragma unroll
  for (int kc = 0; kc < 4; ++kc) {
    af0[kc] = *(const bf16x8*)(a0p + kc * 32);
    af1[kc] = *(const bf16x8*)(a1p + kc * 32);
  }
  f32x4 acc[2][4] = {};
#pragma unroll
  for (int j = 0; j < 4; ++j) {
    const ushort* bp = WTe + (size_t)(y * 128 + n0w + j * 16 + lr) * 128 + quad * 8;
#pragma unroll
    for (int kc = 0; kc < 4; ++kc) {
      bf16x8 bv = *(const bf16x8*)(bp + kc * 32);
      acc[0][j] = __builtin_amdgcn_mfma_f32_16x16x32_bf16(af0[kc], bv, acc[0][j], 0, 0, 0);
      acc[1][j] = __builtin_amdgcn_mfma_f32_16x16x32_bf16(af1[kc], bv, acc[1][j], 0, 0, 0);
    }
  }
  if (y == 0) {
#pragma unroll
    for (int i = 0; i < 2; ++i)
#pragma unroll
      for (int j = 0; j < 4; ++j) {
        int n = n0w + j * 16 + lr;
        float bb = bias[n];
        int mb = gm0 + m0w + i * 16 + quad * 4;
#pragma unroll
        for (int r = 0; r < 4; ++r)
          origin[(size_t)(mb + r) * 128 + n] = f2bf(acc[i][j][r] + bb);
      }
  } else {
    ushort* eT = (y == 1) ? eT0 : (y == 2) ? eT1 : eT2;
    // stage into tr[n][m], 8B packed writes, chunk-XOR swizzle
#pragma unroll
    for (int i = 0; i < 2; ++i)
#pragma unroll
      for (int j = 0; j < 4; ++j) {
        int n = n0w + j * 16 + lr;
        float bb = bias[y * 128 + n];
        int m_lo = m0w + i * 16 + quad * 4;
        int chunk = m_lo >> 3;
        int byteo = n * 128 + ((chunk ^ (n & 7)) << 4) + (m_lo & 7) * 2;
        ushort4 o;
        o.x = f2bf(acc[i][j][0] + bb);
        o.y = f2bf(acc[i][j][1] + bb);
        o.z = f2bf(acc[i][j][2] + bb);
        o.w = f2bf(acc[i][j][3] + bb);
        *(ushort4*)((char*)tr + byteo) = o;
      }
    __syncthreads();
    // store out: thread t covers (n = t>>1, half = t&1): 64B contiguous
    const int n = t >> 1, half = t & 1;
    ushort* gp = eT + (size_t)n * 16384 + gm0 + half * 32;
#pragma unroll
    for (int cc = 0; cc < 4; ++cc) {
      int c = half * 4 + cc;
      uint4 v = *(const uint4*)((char*)tr + n * 128 + ((c ^ (n & 7)) << 4));
      *(uint4*)&gp[cc * 8] = v;
    }
  }
}

// ---------------------------------------------------------------------------
// Masked mean: both operands staged via global_load_lds (deterministic 5 VMEM
// ops/step), double-buffered, raw s_barrier + counted vmcnt(5) (never 0 in
// loop), XOR chunk-swizzled LDS (inverse-swizzled global sources).
// Grid: flat 768 with XCD-aware remap (panel -> fixed XCD for eT L2 reuse).
__global__ __launch_bounds__(256, 3) void k_mm(
    const void* __restrict__ mp, const void* __restrict__ ms,
    const void* __restrict__ mt,
    const ushort* __restrict__ eT0, const ushort* __restrict__ eT1,
    const ushort* __restrict__ eT2,
    ushort* __restrict__ P, ushort* __restrict__ S, ushort* __restrict__ T,
    const int* __restrict__ esz_p) {
  __shared__ ushort Bs[2][8192];   // [128 rows][64 k] per buf, swizzled, 16KB
  __shared__ uchar As1[2][4096];   // [64 rows][64 k] per buf, swizzled, 4KB
  __shared__ uint degs[64];
  const int t = threadIdx.x;
  // XCD remap: panel (b,mid) pinned to XCD g&7; 3 panels x 32 mtiles per XCD.
  const int g = blockIdx.x;
  const int X = g & 7, seq = g >> 3;
  const int pl = seq >> 5, mtile = seq & 31;
  const int panel = pl * 8 + X;
  const int b = panel / 3, mid = panel - b * 3;
  const void* mask = (mid == 0) ? mp : (mid == 1) ? ms : mt;
  const ushort* eT = (mid == 0) ? eT0 : (mid == 1) ? eT1 : eT2;
  ushort* outp = (mid == 0) ? P : (mid == 1) ? S : T;
  const int esz = *esz_p;
  const size_t rowbase = (size_t)b * 2048 + mtile * 64;
  const int lane = t & 63, wave = t >> 6;
  const int m0w = (wave >> 1) * 32, n0w = (wave & 1) * 64;
  const int quad = lane >> 4, lr = lane & 15;
  const int r0 = m0w + lr, r1 = m0w + 16 + lr;  // local tile rows
  f32x4 acc[2][4] = {};
  uint cacc0 = 0, cacc1 = 0;

  if (esz == 1) {
    // ---- staging source addresses (inverse-swizzled) ----
    // B: wave stages rows wave*32+(lane>>3), 8 rows apart per call i;
    //    chunk slot s = lane&7 holds source chunk c = s ^ (row&7).
    const int cB = (lane & 7) ^ (lane >> 3);
    const ushort* gsrcB = eT + (size_t)(wave * 32 + (lane >> 3)) * 16384 +
                          (size_t)b * 2048 + cB * 8;
    // A: wave stages rows wave*16+(lane>>2); 16B chunk slot cs = lane&3 holds
    //    source chunk cs ^ (row&3).
    const int srow = wave * 16 + (lane >> 2);
    const int cA = ((lane & 3) ^ (srow & 3)) << 4;
    const uchar* gsrcA = (const uchar*)mask + (rowbase + srow) * 2048 + cA;
    char* ldsB = (char*)Bs;
    char* ldsA = (char*)As1;

#define STAGEALL(BUF, K0)                                                     \
  {                                                                           \
    _Pragma("unroll") for (int ii = 0; ii < 4; ++ii)                          \
        __builtin_amdgcn_global_load_lds(                                     \
            (const __attribute__((address_space(1))) uint*)(gsrcB +           \
                (size_t)ii * 131072 + (K0)),                                  \
            (__attribute__((address_space(3))) uint*)(ldsB + (BUF) * 16384 +  \
                wave * 4096 + ii * 1024 + lane * 16),                         \
            16, 0, 0);                                                        \
    __builtin_amdgcn_global_load_lds(                                         \
        (const __attribute__((address_space(1))) uint*)(gsrcA + (K0)),        \
        (__attribute__((address_space(3))) uint*)(ldsA + (BUF) * 4096 +       \
            wave * 1024 + lane * 16),                                         \
        16, 0, 0);                                                            \
  }

    // ---- read-side swizzled offsets ----
    const int s0 = quad ^ (lr & 7);
    const int rowb0 = (n0w + 0 * 16 + lr) * 128 + (s0 << 4);
    const int rowb1 = (n0w + 1 * 16 + lr) * 128 + (s0 << 4);
    const int rowb2 = (n0w + 2 * 16 + lr) * 128 + (s0 << 4);
    const int rowb3 = (n0w + 3 * 16 + lr) * 128 + (s0 << 4);
    const int aA0 = r0 * 64 + ((((quad >> 1) ^ (lr & 3))) << 4) + (quad & 1) * 8;
    const int aB0 = aA0 + 16 * 64;  // r1 = r0+16, (r&3) unchanged

#define COMPUTE(BUF)                                                          \
  {                                                                           \
    const char* bb = (const char*)Bs + (BUF) * 16384;                         \
    const char* ab = (const char*)As1 + (BUF) * 4096;                         \
    uint2 wa0 = *(const uint2*)(ab + aA0);                                    \
    uint2 wa1 = *(const uint2*)(ab + (aA0 ^ 32));                             \
    uint2 wb0 = *(const uint2*)(ab + aB0);                                    \
    uint2 wb1 = *(const uint2*)(ab + (aB0 ^ 32));                             \
    bf16x8 b00 = *(const bf16x8*)(bb + rowb0);                                \
    bf16x8 b10 = *(const bf16x8*)(bb + rowb1);                                \
    bf16x8 b20 = *(const bf16x8*)(bb + rowb2);                                \
    bf16x8 b30 = *(const bf16x8*)(bb + rowb3);                                \
    bf16x8 b01 = *(const bf16x8*)(bb + (rowb0 ^ 64));                         \
    bf16x8 b11 = *(const bf16x8*)(bb + (rowb1 ^ 64));                         \
    bf16x8 b21 = *(const bf16x8*)(bb + (rowb2 ^ 64));                         \
    bf16x8 b31 = *(const bf16x8*)(bb + (rowb3 ^ 64));                         \
    bf16x8 a0 = cvt8(wa0.x, wa0.y, cacc0);                                    \
    bf16x8 a1 = cvt8(wb0.x, wb0.y, cacc1);                                    \
    bf16x8 a0h = cvt8(wa1.x, wa1.y, cacc0);                                   \
    bf16x8 a1h = cvt8(wb1.x, wb1.y, cacc1);                                   \
    __builtin_amdgcn_s_setprio(1);                                            \
    acc[0][0] = __builtin_amdgcn_mfma_f32_16x16x32_bf16(a0, b00, acc[0][0], 0, 0, 0); \
    acc[1][0] = __builtin_amdgcn_mfma_f32_16x16x32_bf16(a1, b00, acc[1][0], 0, 0, 0); \
    acc[0][1] = __builtin_amdgcn_mfma_f32_16x16x32_bf16(a0, b10, acc[0][1], 0, 0, 0); \
    acc[1][1] = __builtin_amdgcn_mfma_f32_16x16x32_bf16(a1, b10, acc[1][1], 0, 0, 0); \
    acc[0][2] = __builtin_amdgcn_mfma_f32_16x16x32_bf16(a0, b20, acc[0][2], 0, 0, 0); \
    acc[1][2] = __builtin_amdgcn_mfma_f32_16x16x32_bf16(a1, b20, acc[1][2], 0, 0, 0); \
    acc[0][3] = __builtin_amdgcn_mfma_f32_16x16x32_bf16(a0, b30, acc[0][3], 0, 0, 0); \
    acc[1][3] = __builtin_amdgcn_mfma_f32_16x16x32_bf16(a1, b30, acc[1][3], 0, 0, 0); \
    acc[0][0] = __builtin_amdgcn_mfma_f32_16x16x32_bf16(a0h, b01, acc[0][0], 0, 0, 0); \
    acc[1][0] = __builtin_amdgcn_mfma_f32_16x16x32_bf16(a1h, b01, acc[1][0], 0, 0, 0); \
    acc[0][1] = __builtin_amdgcn_mfma_f32_16x16x32_bf16(a0h, b11, acc[0][1], 0, 0, 0); \
    acc[1][1] = __builtin_amdgcn_mfma_f32_16x16x32_bf16(a1h, b11, acc[1][1], 0, 0, 0); \
    acc[0][2] = __builtin_amdgcn_mfma_f32_16x16x32_bf16(a0h, b21, acc[0][2], 0, 0, 0); \
    acc[1][2] = __builtin_amdgcn_mfma_f32_16x16x32_bf16(a1h, b21, acc[1][2], 0, 0, 0); \
    acc[0][3] = __builtin_amdgcn_mfma_f32_16x16x32_bf16(a0h, b31, acc[0][3], 0, 0, 0); \
    acc[1][3] = __builtin_amdgcn_mfma_f32_16x16x32_bf16(a1h, b31, acc[1][3], 0, 0, 0); \
    __builtin_amdgcn_s_setprio(0);                                            \
  }

#define KITER(BUF, VM)                                                        \
  asm volatile("s_waitcnt vmcnt(" #VM ")" ::: "memory");                      \
  __builtin_amdgcn_s_barrier();                                               \
  __builtin_amdgcn_sched_barrier(0);                                          \
  COMPUTE(BUF);                                                               \
  asm volatile("" ::: "memory");                                              \
  __builtin_amdgcn_s_barrier();

    // prologue: 2 steps in flight (10 VMEM ops)
    STAGEALL(0, 0)
    STAGEALL(1, 64)
    for (int k0 = 0; k0 < 1920; k0 += 128) {
      KITER(0, 5)
      STAGEALL(0, k0 + 128)
      KITER(1, 5)
      STAGEALL(1, k0 + 192)
    }
    KITER(0, 5)   // step 30
    asm volatile("s_waitcnt vmcnt(0)" ::: "memory");
    __builtin_amdgcn_s_barrier();
    __builtin_amdgcn_sched_barrier(0);
    COMPUTE(1)    // step 31
#undef KITER
#undef COMPUTE
#undef STAGEALL
  } else {
    // esz==4 fallback (not the bench's live path): direct-load loop.
    const ushort* bp0 = eT + (size_t)(n0w + lr) * 16384 + (size_t)b * 2048 + quad * 8;
    const ushort* bp1 = bp0 + 16 * 16384;
    const ushort* bp2 = bp0 + 32 * 16384;
    const ushort* bp3 = bp0 + 48 * 16384;
    const uint* ma = (const uint*)mask + (rowbase + r0) * 2048 + quad * 8;
    const uint* mb = (const uint*)mask + (rowbase + r1) * 2048 + quad * 8;
    for (int k0 = 0; k0 < 2048; k0 += 64) {
#pragma unroll
      for (int kc = 0; kc < 2; ++kc) {
        uint4 wa0 = *(const uint4*)(ma + k0 + kc * 32);
        uint4 wa1 = *(const uint4*)(ma + k0 + kc * 32 + 4);
        uint4 wb0 = *(const uint4*)(mb + k0 + kc * 32);
        uint4 wb1 = *(const uint4*)(mb + k0 + kc * 32 + 4);
        bf16x8 bv0 = *(const bf16x8*)(bp0 + k0 + kc * 32);
        bf16x8 bv1 = *(const bf16x8*)(bp1 + k0 + kc * 32);
        bf16x8 bv2 = *(const bf16x8*)(bp2 + k0 + kc * 32);
        bf16x8 bv3 = *(const bf16x8*)(bp3 + k0 + kc * 32);
        bf16x8 a0 = cvt8w(wa0, wa1, cacc0);
        bf16x8 a1 = cvt8w(wb0, wb1, cacc1);
        acc[0][0] = __builtin_amdgcn_mfma_f32_16x16x32_bf16(a0, bv0, acc[0][0], 0, 0, 0);
        acc[1][0] = __builtin_amdgcn_mfma_f32_16x16x32_bf16(a1, bv0, acc[1][0], 0, 0, 0);
        acc[0][1] = __builtin_amdgcn_mfma_f32_16x16x32_bf16(a0, bv1, acc[0][1], 0, 0, 0);
        acc[1][1] = __builtin_amdgcn_mfma_f32_16x16x32_bf16(a1, bv1, acc[1][1], 0, 0, 0);
        acc[0][2] = __builtin_amdgcn_mfma_f32_16x16x32_bf16(a0, bv2, acc[0][2], 0, 0, 0);
        acc[1][2] = __builtin_amdgcn_mfma_f32_16x16x32_bf16(a1, bv2, acc[1][2], 0, 0, 0);
        acc[0][3] = __builtin_amdgcn_mfma_f32_16x16x32_bf16(a0, bv3, acc[0][3], 0, 0, 0);
        acc[1][3] = __builtin_amdgcn_mfma_f32_16x16x32_bf16(a1, bv3, acc[1][3], 0, 0, 0);
      }
    }
  }

  // Degree: per-thread partials (rows r0, r1) -> sum over the 4 quad lanes.
  int c0, c1;
  if (esz == 1) {
    c0 = (int)((cacc0 & 0xFFFFu) + (cacc0 >> 16));
    c1 = (int)((cacc1 & 0xFFFFu) + (cacc1 >> 16));
  } else {
    c0 = (int)cacc0;
    c1 = (int)cacc1;
  }
  c0 += __shfl_xor(c0, 16); c0 += __shfl_xor(c0, 32);
  c1 += __shfl_xor(c1, 16); c1 += __shfl_xor(c1, 32);
  if ((wave & 1) == 0 && quad == 0) { degs[r0] = (uint)c0; degs[r1] = (uint)c1; }
  __syncthreads();

#pragma unroll
  for (int i = 0; i < 2; ++i)
#pragma unroll
    for (int r = 0; r < 4; ++r) {
      int ml = m0w + i * 16 + quad * 4 + r;
      uint d = degs[ml];
      float inv = 1.0f / (float)(d > 0u ? d : 1u);
#pragma unroll
      for (int j = 0; j < 4; ++j) {
        int n = n0w + j * 16 + lr;
        outp[(rowbase + ml) * 128 + n] = f2bf(acc[i][j][r] * inv);
      }
    }
}

// ---------------------------------------------------------------------------
// Generic LDS-free GEMM body (small K; all data L2-resident).
__device__ __forceinline__ void gemm_body(
    const ushort* __restrict__ A0, const ushort* __restrict__ A1,
    const ushort* __restrict__ A2, const ushort* __restrict__ Bsrc,
    int bstride, int K, const float* __restrict__ bias,
    void* __restrict__ out, int out_f32, int gm0, int t) {
  const int lane = t & 63, wave = t >> 6;
  const int m0w = (wave >> 1) * 32, n0w = (wave & 1) * 64;
  const int quad = lane >> 4, lr = lane & 15;
  const ushort* bbase = Bsrc + (size_t)(n0w + lr) * bstride + quad * 8;
  f32x4 acc[2][4] = {};
  for (int k0 = 0; k0 < K; k0 += 64) {
    const int seg = k0 >> 7;
    const ushort* Ap = (seg == 0) ? A0 : (seg == 1) ? A1 : A2;
    const int ko = k0 & 127;
    const ushort* a0p = Ap + (size_t)(gm0 + m0w + lr) * 128 + ko + quad * 8;
    const ushort* a1p = a0p + 16 * 128;
#pragma unroll
    for (int kc = 0; kc < 2; ++kc) {
      bf16x8 av0 = *(const bf16x8*)(a0p + kc * 32);
      bf16x8 av1 = *(const bf16x8*)(a1p + kc * 32);
      bf16x8 b0 = *(const bf16x8*)(bbase + k0 + kc * 32);
      bf16x8 b1 = *(const bf16x8*)(bbase + (size_t)16 * bstride + k0 + kc * 32);
      bf16x8 b2 = *(const bf16x8*)(bbase + (size_t)32 * bstride + k0 + kc * 32);
      bf16x8 b3 = *(const bf16x8*)(bbase + (size_t)48 * bstride + k0 + kc * 32);
      acc[0][0] = __builtin_amdgcn_mfma_f32_16x16x32_bf16(av0, b0, acc[0][0], 0, 0, 0);
      acc[1][0] = __builtin_amdgcn_mfma_f32_16x16x32_bf16(av1, b0, acc[1][0], 0, 0, 0);
      acc[0][1] = __builtin_amdgcn_mfma_f32_16x16x32_bf16(av0, b1, acc[0][1], 0, 0, 0);
      acc[1][1] = __builtin_amdgcn_mfma_f32_16x16x32_bf16(av1, b1, acc[1][1], 0, 0, 0);
      acc[0][2] = __builtin_amdgcn_mfma_f32_16x16x32_bf16(av0, b2, acc[0][2], 0, 0, 0);
      acc[1][2] = __builtin_amdgcn_mfma_f32_16x16x32_bf16(av1, b2, acc[1][2], 0, 0, 0);
      acc[0][3] = __builtin_amdgcn_mfma_f32_16x16x32_bf16(av0, b3, acc[0][3], 0, 0, 0);
      acc[1][3] = __builtin_amdgcn_mfma_f32_16x16x32_bf16(av1, b3, acc[1][3], 0, 0, 0);
    }
  }
#pragma unroll
  for (int i = 0; i < 2; ++i)
#pragma unroll
    for (int j = 0; j < 4; ++j) {
      const int n = n0w + j * 16 + lr;
      const float bb = bias[n];
      const int mb = gm0 + m0w + i * 16 + quad * 4;
      if (out_f32) {
#pragma unroll
        for (int r = 0; r < 4; ++r)
          ((float*)out)[(size_t)(mb + r) * 128 + n] = acc[i][j][r] + bb;
      } else {
#pragma unroll
        for (int r = 0; r < 4; ++r)
          ((ushort*)out)[(size_t)(mb + r) * 128 + n] = f2bf(acc[i][j][r] + bb);
      }
    }
}

__global__ __launch_bounds__(256) void k_xy(
    const ushort* __restrict__ P, const ushort* __restrict__ origin,
    const ushort* __restrict__ S, const ushort* __restrict__ T,
    const ushort* __restrict__ WTs, const ushort* __restrict__ WTm,
    const float* __restrict__ bs, const float* __restrict__ bm,
    ushort* __restrict__ X, ushort* __restrict__ Y) {
  const int gm0 = blockIdx.x * 64;
  if (blockIdx.y == 0)
    gemm_body(P, origin, S, WTs, 384, 384, bs, X, 0, gm0, threadIdx.x);
  else
    gemm_body(origin, T, nullptr, WTm, 256, 256, bm, Y, 0, gm0, threadIdx.x);
}

__global__ __launch_bounds__(256) void k_mix(
    const ushort* __restrict__ X, const ushort* __restrict__ Y,
    const ushort* __restrict__ WTx, const float* __restrict__ bx,
    float* __restrict__ out) {
  gemm_body(X, Y, nullptr, WTx, 256, 256, bx, out, 1, blockIdx.x * 64, threadIdx.x);
}

// ---------------------------------------------------------------------------
extern "C" void kernel_launch(void* const* d_in, const int* in_sizes, int n_in,
                              void* d_out, int out_size, void* d_ws,
                              size_t ws_size, hipStream_t stream) {
  const float* features = (const float*)d_in[0];
  const void* pred = d_in[1];
  const void* succ = d_in[2];
  const void* same = d_in[3];
  const float* W_enc = (const float*)d_in[4];
  const float* b_enc = (const float*)d_in[5];
  const float* W_space = (const float*)d_in[6];
  const float* b_space = (const float*)d_in[7];
  const float* W_same = (const float*)d_in[8];
  const float* b_same = (const float*)d_in[9];
  const float* W_mix = (const float*)d_in[10];
  const float* b_mix = (const float*)d_in[11];

  const size_t M = 16384;
  ushort* w = (ushort*)d_ws;
  ushort* feat_bf = w;  w += M * 128;
  ushort* WT_enc = w;   w += 512 * 128;
  ushort* WT_space = w; w += 128 * 384;
  ushort* WT_same = w;  w += 128 * 256;
  ushort* WT_mix = w;   w += 128 * 256;
  ushort* origin = w;   w += M * 128;
  ushort* eT0 = w;      w += M * 128;
  ushort* eT1 = w;      w += M * 128;
  ushort* eT2 = w;      w += M * 128;
  ushort* P = w;        w += M * 128;
  ushort* S = w;        w += M * 128;
  ushort* T = w;        w += M * 128;
  ushort* X = w;        w += M * 128;
  ushort* Y = w;        w += M * 128;
  int* esz = (int*)w;

  k_detect<<<1, 256, 0, stream>>>((const uint4*)pred, esz);
  k_prep<<<704, 256, 0, stream>>>((const float4*)features, feat_bf,
                                  W_enc, W_space, W_same, W_mix,
                                  WT_enc, WT_space, WT_same, WT_mix);
  k_enc<<<dim3(256, 4), 256, 0, stream>>>(feat_bf, WT_enc, b_enc,
                                          origin, eT0, eT1, eT2);
  k_mm<<<768, 256, 0, stream>>>(pred, succ, same, eT0, eT1, eT2,
                                P, S, T, esz);
  k_xy<<<dim3(256, 2), 256, 0, stream>>>(P, origin, S, T, WT_space, WT_same,
                                         b_space, b_same, X, Y);
  k_mix<<<256, 256, 0, stream>>>(X, Y, WT_mix, b_mix, (float*)d_out);
}